// Round 4
// baseline (51.136 us; speedup 1.0000x reference)
//
#include <hip/hip_runtime.h>
#include <stdint.h>

#define EPS 1e-5f
#define T_DIM 16384
#define N_DIM 1024
#define K_DIM 1024

// ---------------- workspace layout (bytes) ----------------
// qx   int8  [16384][1024]  @ 0          (16 MiB)
// qw   int8  [1024][1024]   @ 16777216   (1 MiB)
// dq   f32   [16384]        @ 17825792   (64 KiB)   dq[t] = max(rowmax,EPS)/127
// part f64   [256]          @ 17891328   (2 KiB)
// meanf f32  [1]            @ 17893376

typedef int v4i __attribute__((ext_vector_type(4)));

// ---------- kernel 1: wave-per-row x-quant (blocks 0..4095) + |W| partial
// sums (blocks 4096..4351) ----------
// Row assignment is XCD-aligned with k_gemm: block bid (round-robin xcd =
// bid&7) handles row-block (bid&7)*512 + (bid>>3), so xcd x writes qx rows
// [x*2048,(x+1)*2048) into its own L2 -- exactly the slab k_gemm's xcd x
// reads. Perf heuristic only; bijective on [0,4096).
__global__ __launch_bounds__(256) void k_xq_wabs(
    const float* __restrict__ x, const float* __restrict__ w,
    char* __restrict__ qx, float* __restrict__ dq, double* __restrict__ part) {
    const int bid = blockIdx.x;
    const int tid = threadIdx.x;

    if (bid < 4096) {
        // ---- per-row absmax + int8 quantize, one wave per row ----
        const int rb   = (bid & 7) * 512 + (bid >> 3);
        const int row  = rb * 4 + (tid >> 6);
        const int lane = tid & 63;
        const float4* xr = (const float4*)(x + (long)row * K_DIM);
        float4 v[4];
#pragma unroll
        for (int i = 0; i < 4; ++i) v[i] = xr[i * 64 + lane];
        float m = 0.0f;
#pragma unroll
        for (int i = 0; i < 4; ++i)
            m = fmaxf(m, fmaxf(fmaxf(fabsf(v[i].x), fabsf(v[i].y)),
                               fmaxf(fabsf(v[i].z), fabsf(v[i].w))));
#pragma unroll
        for (int s = 32; s > 0; s >>= 1) m = fmaxf(m, __shfl_xor(m, s));
        m = fmaxf(m, EPS);                        // jnp.clip(rowmax, EPS)
        if (lane == 0) dq[row] = m * (1.0f / 127.0f);
        const float s = 127.0f / m;               // act_scale
        int* qrow = (int*)(qx + (long)row * K_DIM);
#pragma unroll
        for (int i = 0; i < 4; ++i) {
            float f0 = fminf(fmaxf(rintf(v[i].x * s), -128.f), 127.f);
            float f1 = fminf(fmaxf(rintf(v[i].y * s), -128.f), 127.f);
            float f2 = fminf(fmaxf(rintf(v[i].z * s), -128.f), 127.f);
            float f3 = fminf(fmaxf(rintf(v[i].w * s), -128.f), 127.f);
            int q0 = (int)f0, q1 = (int)f1, q2 = (int)f2, q3 = (int)f3;
            qrow[i * 64 + lane] = (q0 & 255) | ((q1 & 255) << 8) |
                                  ((q2 & 255) << 16) | ((q3 & 255) << 24);
        }
    } else {
        // ---- partial |W| sums, f64, deterministic ----
        const int wb = bid - 4096;               // 0..255
        const int base = wb * 256 + tid;         // over 262144 float4
        const float4* w4 = (const float4*)w;
        double sum = 0.0;
#pragma unroll
        for (int i = 0; i < 4; ++i) {
            float4 v = w4[base + i * 65536];
            sum += (double)fabsf(v.x) + (double)fabsf(v.y) +
                   (double)fabsf(v.z) + (double)fabsf(v.w);
        }
        __shared__ double redd[256];
        redd[tid] = sum;
        __syncthreads();
#pragma unroll
        for (int st = 128; st > 0; st >>= 1) {
            if (tid < st) redd[tid] += redd[tid + st];
            __syncthreads();
        }
        if (tid == 0) part[wb] = redd[0];
    }
}

// ---------- kernel 2: finalize mean (redundant per block, deterministic)
//            + ternary-quantize W ----------
__global__ __launch_bounds__(256) void k_wquant(
    const float* __restrict__ w, char* __restrict__ qw,
    const double* __restrict__ part, float* __restrict__ meanf) {
    const int tid = threadIdx.x;
    __shared__ double red[256];
    red[tid] = part[tid];
    __syncthreads();
#pragma unroll
    for (int st = 128; st > 0; st >>= 1) {
        if (tid < st) red[tid] += red[tid + st];
        __syncthreads();
    }
    const double mean = fmax(red[0] / 1048576.0, (double)EPS);  // clip(mean,EPS)
    if (blockIdx.x == 0 && tid == 0) meanf[0] = (float)mean;
    const double ws = 1.0 / mean;                // w_scale
    const long i = (long)blockIdx.x * 256 + tid; // 262144 float4
    float4 v = ((const float4*)w)[i];
    int q0 = (int)rint((double)v.x * ws);
    int q1 = (int)rint((double)v.y * ws);
    int q2 = (int)rint((double)v.z * ws);
    int q3 = (int)rint((double)v.w * ws);
    q0 = max(-1, min(1, q0)); q1 = max(-1, min(1, q1));
    q2 = max(-1, min(1, q2)); q3 = max(-1, min(1, q3));
    int packed = (q0 & 255) | ((q1 & 255) << 8) | ((q2 & 255) << 16) | ((q3 & 255) << 24);
    ((int*)qw)[i] = packed;
}

// ---------- kernel 3: i8 GEMM, two 256x128 sub-tiles per block ----------
// R0's K-loop geometry (1 blk/CU, BK=128, 16x16x64 MFMA, 2-phase sync) kept
// intact; each block runs TWO sequential sub-tiles sharing the A-slab (same
// brow, adjacent bcols). Sub-tile A's stores are issued between the loops:
// global_store acks at L2 on gfx9, so A's 32 MiB HBM drain overlaps sub-tile
// B's K-loop instead of serializing after all compute.
#define BM 256
#define BN 128
#define BK 128

__device__ __forceinline__ void gld_lds16(const void* g, void* l) {
    __builtin_amdgcn_global_load_lds(
        (const __attribute__((address_space(1))) void*)g,
        (__attribute__((address_space(3))) void*)l, 16, 0, 0);
}

__global__ __launch_bounds__(512, 2) void k_gemm(
    const char* __restrict__ qx, const char* __restrict__ qw,
    const float* __restrict__ dq, const float* __restrict__ meanf_p,
    const float* __restrict__ bias, float* __restrict__ out) {
    __shared__ __attribute__((aligned(16))) char As[2][BM * BK];   // 2 x 32 KiB
    __shared__ __attribute__((aligned(16))) char Bs[2][BN * BK];   // 2 x 16 KiB

    const int tid  = threadIdx.x;
    const int lane = tid & 63;
    const int wid  = tid >> 6;
    const int wr   = wid >> 1;          // 4x2 wave grid; wave tile 64x64
    const int wc   = wid & 1;

    // 256 blocks = 64 brow x 4 bcol-pairs. XCD-bijective remap: xcd = bid&7
    // owns works xcd*32..+31 = 8 consecutive brows x 4 pairs -> 2 MiB qx slab
    // (written by the same xcd in k1) + 1 MiB qw per XCD L2.
    const int bid  = blockIdx.x;
    const int work = (bid & 7) * 32 + (bid >> 3);
    const int brow = work >> 2;
    const int bcp  = work & 3;
    const long arow0 = (long)brow * BM;
    const int  ncol0 = bcp * 256;       // two 128-col sub-tiles

    // staging: off = tid*16 + p*8192; row = off/128, chunk = (off/16)&7.
    // A uses p=0..3 (32 KiB), B uses p=0..1 (16 KiB).
    // Swizzle involution S(row,c) = c ^ (row&7) on global source AND on read
    // (rule #21): LDS[row][ch] holds G[row][ch ^ (row&7)].
    int s_row[4], s_src[4], s_off[4];
#pragma unroll
    for (int p = 0; p < 4; ++p) {
        int off = tid * 16 + p * 8192;
        int row = off >> 7;
        int ch  = (off >> 4) & 7;
        s_row[p] = row; s_src[p] = (ch ^ (row & 7)) * 16; s_off[p] = off;
    }

#define STAGE(k0_, buf_, nc_)                                                 \
    {                                                                         \
        _Pragma("unroll")                                                     \
        for (int p = 0; p < 4; ++p) {                                         \
            const char* gA = qx + ((arow0 + s_row[p]) << 10) + (k0_) + s_src[p]; \
            gld_lds16(gA, As[buf_] + s_off[p]);                               \
        }                                                                     \
        _Pragma("unroll")                                                     \
        for (int p = 0; p < 2; ++p) {                                         \
            const char* gB = qw + (((long)((nc_) + s_row[p])) << 10) + (k0_) + s_src[p]; \
            gld_lds16(gB, Bs[buf_] + s_off[p]);                               \
        }                                                                     \
    }

    v4i acc[4][4] = {};

    const int r15 = lane & 15;
    const int cg  = lane >> 4;          // k-chunk group 0..3
    const int sw  = lane & 7;           // read-side swizzle (row&7 == lane&7)

#define COMPUTE(cur_)                                                         \
    {                                                                         \
        _Pragma("unroll")                                                     \
        for (int ks = 0; ks < 2; ++ks) {                                      \
            const int c   = ks * 4 + cg;                                      \
            const int rch = (c ^ sw) * 16;                                    \
            v4i a[4], b[4];                                                   \
            _Pragma("unroll")                                                 \
            for (int m = 0; m < 4; ++m) {                                     \
                int row = wr * 64 + m * 16 + r15;                             \
                a[m] = *(const v4i*)(As[cur_] + row * BK + rch);              \
            }                                                                 \
            _Pragma("unroll")                                                 \
            for (int n = 0; n < 4; ++n) {                                     \
                int row = wc * 64 + n * 16 + r15;                             \
                b[n] = *(const v4i*)(Bs[cur_] + row * BK + rch);              \
            }                                                                 \
            _Pragma("unroll")                                                 \
            for (int m = 0; m < 4; ++m)                                       \
                _Pragma("unroll")                                             \
                for (int n = 0; n < 4; ++n)                                   \
                    acc[m][n] = __builtin_amdgcn_mfma_i32_16x16x64_i8(        \
                        a[m], b[n], acc[m][n], 0, 0, 0);                      \
        }                                                                     \
    }

    // epilogue: C/D layout col=lane&15, row=(lane>>4)*4+reg
#define EPI(nc_)                                                              \
    {                                                                         \
        const int ocol = (nc_) + wc * 64 + r15;                               \
        float bv[4];                                                          \
        _Pragma("unroll")                                                     \
        for (int n = 0; n < 4; ++n) bv[n] = bias[ocol + n * 16];              \
        _Pragma("unroll")                                                     \
        for (int m = 0; m < 4; ++m) {                                         \
            _Pragma("unroll")                                                 \
            for (int rr = 0; rr < 4; ++rr) {                                  \
                long orow = arow0 + wr * 64 + m * 16 + cg * 4 + rr;           \
                float d = dq[orow] * wmean;                                   \
                _Pragma("unroll")                                             \
                for (int n = 0; n < 4; ++n)                                   \
                    out[orow * N_DIM + ocol + n * 16] =                       \
                        (float)acc[m][n][rr] * d + bv[n];                     \
            }                                                                 \
        }                                                                     \
    }

    const float wmean = meanf_p[0];

    STAGE(0, 0, ncol0);
    __syncthreads();

    // ---- sub-tile 0 (cols ncol0 .. ncol0+127) ----
#pragma unroll
    for (int k0 = 0; k0 < 8; ++k0) {
        const int cur = k0 & 1;
        if (k0 < 7) STAGE((k0 + 1) * BK, cur ^ 1, ncol0)
        else        STAGE(0,             cur ^ 1, ncol0 + 128);  // tile1 step0
        COMPUTE(cur);
        __syncthreads();
    }

    EPI(ncol0);           // stores issued; HBM drain overlaps sub-tile 1
#pragma unroll
    for (int m = 0; m < 4; ++m)
#pragma unroll
        for (int n = 0; n < 4; ++n) acc[m][n] = (v4i)(0);

    // ---- sub-tile 1 (cols ncol0+128 .. ncol0+255); step0 already in buf0 ----
#pragma unroll
    for (int k0 = 0; k0 < 8; ++k0) {
        const int cur = k0 & 1;
        if (k0 < 7) STAGE((k0 + 1) * BK, cur ^ 1, ncol0 + 128);
        COMPUTE(cur);
        __syncthreads();
    }

    EPI(ncol0 + 128);
}

extern "C" void kernel_launch(void* const* d_in, const int* in_sizes, int n_in,
                              void* d_out, int out_size, void* d_ws, size_t ws_size,
                              hipStream_t stream) {
    (void)in_sizes; (void)n_in; (void)out_size; (void)ws_size;
    const float* x    = (const float*)d_in[0];
    const float* w    = (const float*)d_in[1];
    const float* bias = (const float*)d_in[2];
    float* out = (float*)d_out;

    char*   ws    = (char*)d_ws;
    char*   qx    = ws;
    char*   qw    = ws + 16777216;
    float*  dq    = (float*)(ws + 17825792);
    double* part  = (double*)(ws + 17891328);
    float*  meanf = (float*)(ws + 17893376);

    k_xq_wabs<<<dim3(4096 + 256), dim3(256), 0, stream>>>(x, w, qx, dq, part);
    k_wquant <<<dim3(1024),       dim3(256), 0, stream>>>(w, qw, part, meanf);
    k_gemm   <<<dim3(256),        dim3(512), 0, stream>>>(qx, qw, dq, meanf, bias, out);
}

// Round 5
// 46.769 us; speedup vs baseline: 1.0934x; 1.0934x over previous
//
#include <hip/hip_runtime.h>
#include <stdint.h>

#define EPS 1e-5f
#define T_DIM 16384
#define N_DIM 1024
#define K_DIM 1024

// ---------------- workspace layout (bytes) ----------------
// qx   int8  [16384][1024]  @ 0          (16 MiB)
// qw   int8  [1024][1024]   @ 16777216   (1 MiB)
// dq   f32   [16384]        @ 17825792   (64 KiB)   dq[t] = max(rowmax,EPS)/127
// part f64   [256]          @ 17891328   (2 KiB)
// meanf f32  [1]            @ 17893376

typedef int v4i __attribute__((ext_vector_type(4)));

// ---------- kernel 1: wave-per-row x-quant (blocks 0..4095) + |W| partial
// sums (blocks 4096..4351) ----------
// Row assignment XCD-aligned with k_gemm: xcd x writes qx rows
// [x*2048,(x+1)*2048) into its own L2 -- the slab k_gemm's xcd x reads.
__global__ __launch_bounds__(256) void k_xq_wabs(
    const float* __restrict__ x, const float* __restrict__ w,
    char* __restrict__ qx, float* __restrict__ dq, double* __restrict__ part) {
    const int bid = blockIdx.x;
    const int tid = threadIdx.x;

    if (bid < 4096) {
        // ---- per-row absmax + int8 quantize, one wave per row ----
        const int rb   = (bid & 7) * 512 + (bid >> 3);
        const int row  = rb * 4 + (tid >> 6);
        const int lane = tid & 63;
        const float4* xr = (const float4*)(x + (long)row * K_DIM);
        float4 v[4];
#pragma unroll
        for (int i = 0; i < 4; ++i) v[i] = xr[i * 64 + lane];
        float m = 0.0f;
#pragma unroll
        for (int i = 0; i < 4; ++i)
            m = fmaxf(m, fmaxf(fmaxf(fabsf(v[i].x), fabsf(v[i].y)),
                               fmaxf(fabsf(v[i].z), fabsf(v[i].w))));
#pragma unroll
        for (int s = 32; s > 0; s >>= 1) m = fmaxf(m, __shfl_xor(m, s));
        m = fmaxf(m, EPS);                        // jnp.clip(rowmax, EPS)
        if (lane == 0) dq[row] = m * (1.0f / 127.0f);
        const float s = 127.0f / m;               // act_scale
        int* qrow = (int*)(qx + (long)row * K_DIM);
#pragma unroll
        for (int i = 0; i < 4; ++i) {
            float f0 = fminf(fmaxf(rintf(v[i].x * s), -128.f), 127.f);
            float f1 = fminf(fmaxf(rintf(v[i].y * s), -128.f), 127.f);
            float f2 = fminf(fmaxf(rintf(v[i].z * s), -128.f), 127.f);
            float f3 = fminf(fmaxf(rintf(v[i].w * s), -128.f), 127.f);
            int q0 = (int)f0, q1 = (int)f1, q2 = (int)f2, q3 = (int)f3;
            qrow[i * 64 + lane] = (q0 & 255) | ((q1 & 255) << 8) |
                                  ((q2 & 255) << 16) | ((q3 & 255) << 24);
        }
    } else {
        // ---- partial |W| sums, f64, deterministic ----
        const int wb = bid - 4096;               // 0..255
        const int base = wb * 256 + tid;         // over 262144 float4
        const float4* w4 = (const float4*)w;
        double sum = 0.0;
#pragma unroll
        for (int i = 0; i < 4; ++i) {
            float4 v = w4[base + i * 65536];
            sum += (double)fabsf(v.x) + (double)fabsf(v.y) +
                   (double)fabsf(v.z) + (double)fabsf(v.w);
        }
        __shared__ double redd[256];
        redd[tid] = sum;
        __syncthreads();
#pragma unroll
        for (int st = 128; st > 0; st >>= 1) {
            if (tid < st) redd[tid] += redd[tid + st];
            __syncthreads();
        }
        if (tid == 0) part[wb] = redd[0];
    }
}

// ---------- kernel 2: finalize mean (redundant per block, deterministic)
//            + ternary-quantize W ----------
__global__ __launch_bounds__(256) void k_wquant(
    const float* __restrict__ w, char* __restrict__ qw,
    const double* __restrict__ part, float* __restrict__ meanf) {
    const int tid = threadIdx.x;
    __shared__ double red[256];
    red[tid] = part[tid];
    __syncthreads();
#pragma unroll
    for (int st = 128; st > 0; st >>= 1) {
        if (tid < st) red[tid] += red[tid + st];
        __syncthreads();
    }
    const double mean = fmax(red[0] / 1048576.0, (double)EPS);  // clip(mean,EPS)
    if (blockIdx.x == 0 && tid == 0) meanf[0] = (float)mean;
    const double ws = 1.0 / mean;                // w_scale
    const long i = (long)blockIdx.x * 256 + tid; // 262144 float4
    float4 v = ((const float4*)w)[i];
    int q0 = (int)rint((double)v.x * ws);
    int q1 = (int)rint((double)v.y * ws);
    int q2 = (int)rint((double)v.z * ws);
    int q3 = (int)rint((double)v.w * ws);
    q0 = max(-1, min(1, q0)); q1 = max(-1, min(1, q1));
    q2 = max(-1, min(1, q2)); q3 = max(-1, min(1, q3));
    int packed = (q0 & 255) | ((q1 & 255) << 8) | ((q2 & 255) << 16) | ((q3 & 255) << 24);
    ((int*)qw)[i] = packed;
}

// ---------- kernel 3: i8 GEMM, 256x256 tile, BK=64, quad-buffer, counted vmcnt ----
// R0's geometry (8 waves 2x4, wave tile 128x64, 16x16x64 MFMA, same epilogue)
// with T3+T4: K split into 16 tiles of 64, 4 LDS buffers (mod-4: iter t reads
// buf[t&3], stages buf[(t+2)&3] -- disjoint even with +-1 wave drift), one
// barrier/iter with s_waitcnt vmcnt(4) (NEVER 0 in steady state): loads stay
// in flight across barriers instead of R0's full drain every K-step.
// Per wave per iter: 12 ds_read_b128, 4 global_load_lds, 32 MFMA in two
// setprio(1) clusters (T5 pays on phase-split schedules).
#define BM 256
#define BN 256
#define BK 64
#define TILE_B (BM * BK)          // 16 KiB per matrix per buffer

__device__ __forceinline__ void gld_lds16(const void* g, void* l) {
    __builtin_amdgcn_global_load_lds(
        (const __attribute__((address_space(1))) void*)g,
        (__attribute__((address_space(3))) void*)l, 16, 0, 0);
}

__global__ __launch_bounds__(512, 2) void k_gemm(
    const char* __restrict__ qx, const char* __restrict__ qw,
    const float* __restrict__ dq, const float* __restrict__ meanf_p,
    const float* __restrict__ bias, float* __restrict__ out) {
    __shared__ __attribute__((aligned(16))) char As[4][TILE_B];   // 64 KiB
    __shared__ __attribute__((aligned(16))) char Bs[4][TILE_B];   // 64 KiB

    const int tid  = threadIdx.x;
    const int lane = tid & 63;
    const int wid  = tid >> 6;
    const int wr   = wid >> 2;          // 2x4 wave grid; wave tile 128x64
    const int wc   = wid & 3;

    // 256 blocks = 64 brow x 4 bcol. XCD-bijective remap: xcd = bid&7 owns
    // works xcd*32..+31 = 8 consecutive brows x 4 bcols -> 2 MiB qx slab
    // (written by the same xcd in k1) + 1 MiB qw per XCD L2.
    const int bid  = blockIdx.x;
    const int work = (bid & 7) * 32 + (bid >> 3);
    const int brow = work >> 2;
    const int bcol = work & 3;
    const long arow0 = (long)brow * BM;
    const int  ncol0 = bcol * BN;

    // staging: 16 KiB tile = 2 passes of 512 thr x 16 B. off = tid*16+p*8192,
    // row = off/64 (64 B rows), chunk = (off/16)&3. Swizzle involution
    // S(row,c) = c ^ (row&3) applied on global source AND on read (rule #21).
    // Bank check: read starts 16*(row&1)+4*(cg^(row&3)) cover all 8 slots x
    // 8 lanes uniformly -> balanced, conflict-free.
    int s_row[2], s_src[2], s_off[2];
#pragma unroll
    for (int p = 0; p < 2; ++p) {
        int off = tid * 16 + p * 8192;
        int row = off >> 6;
        int ch  = (off >> 4) & 3;
        s_row[p] = row; s_src[p] = (ch ^ (row & 3)) * 16; s_off[p] = off;
    }

#define STAGE_A(kt_, buf_)                                                    \
    {                                                                         \
        _Pragma("unroll")                                                     \
        for (int p = 0; p < 2; ++p) {                                         \
            const char* g = qx + ((arow0 + s_row[p]) << 10) + (kt_) * 64 + s_src[p]; \
            gld_lds16(g, As[buf_] + s_off[p]);                                \
        }                                                                     \
    }
#define STAGE_B(kt_, buf_)                                                    \
    {                                                                         \
        _Pragma("unroll")                                                     \
        for (int p = 0; p < 2; ++p) {                                         \
            const char* g = qw + (((long)(ncol0 + s_row[p])) << 10) + (kt_) * 64 + s_src[p]; \
            gld_lds16(g, Bs[buf_] + s_off[p]);                                \
        }                                                                     \
    }

    v4i acc[8][4] = {};

    const int r15 = lane & 15;
    const int cg  = lane >> 4;                    // 16 B k-chunk 0..3
    const int rch = ((cg ^ (r15 & 3)) & 3) * 16;  // swizzled byte chunk in row

    // prologue: tiles 0,1 in flight (8 loads); vmcnt(4) => tile 0 resident
    STAGE_A(0, 0); STAGE_B(0, 0);
    STAGE_A(1, 1); STAGE_B(1, 1);
    asm volatile("s_waitcnt vmcnt(4)" ::: "memory");
    __builtin_amdgcn_s_barrier();

#pragma unroll
    for (int t = 0; t < 16; ++t) {               // K-tiles of 64
        const int cur = t & 3;
        const char* Ab = As[cur];
        const char* Bb = Bs[cur];

        // ---- phase 1: b all, a rows 0..3; stage A(t+2); 16 MFMA ----
        v4i a[4], b[4];
#pragma unroll
        for (int n = 0; n < 4; ++n)
            b[n] = *(const v4i*)(Bb + (wc * 64 + n * 16 + r15) * BK + rch);
#pragma unroll
        for (int m = 0; m < 4; ++m)
            a[m] = *(const v4i*)(Ab + (wr * 128 + m * 16 + r15) * BK + rch);
        if (t < 14) STAGE_A(t + 2, (t + 2) & 3);
        __builtin_amdgcn_s_setprio(1);
#pragma unroll
        for (int m = 0; m < 4; ++m)
#pragma unroll
            for (int n = 0; n < 4; ++n)
                acc[m][n] = __builtin_amdgcn_mfma_i32_16x16x64_i8(
                    a[m], b[n], acc[m][n], 0, 0, 0);
        __builtin_amdgcn_s_setprio(0);

        // ---- phase 2: a rows 4..7; stage B(t+2); 16 MFMA ----
#pragma unroll
        for (int m = 0; m < 4; ++m)
            a[m] = *(const v4i*)(Ab + (wr * 128 + (m + 4) * 16 + r15) * BK + rch);
        if (t < 14) STAGE_B(t + 2, (t + 2) & 3);
        __builtin_amdgcn_s_setprio(1);
#pragma unroll
        for (int m = 0; m < 4; ++m)
#pragma unroll
            for (int n = 0; n < 4; ++n)
                acc[m + 4][n] = __builtin_amdgcn_mfma_i32_16x16x64_i8(
                    a[m], b[n], acc[m + 4][n], 0, 0, 0);
        __builtin_amdgcn_s_setprio(0);

        // ---- tile boundary: prove tile t+1 resident, never full-drain ----
        // queue: tile t+1's 4 loads + tile t+2's 4 just issued -> vmcnt(4).
        // t==14: nothing issued after tile 15's loads -> vmcnt(0). t==15: none.
        if (t < 14) {
            asm volatile("s_waitcnt vmcnt(4)" ::: "memory");
            __builtin_amdgcn_s_barrier();
        } else if (t == 14) {
            asm volatile("s_waitcnt vmcnt(0)" ::: "memory");
            __builtin_amdgcn_s_barrier();
        }
    }

    // epilogue: C/D layout col=lane&15, row=(lane>>4)*4+reg  (unchanged R0)
    const float wmean = meanf_p[0];
    const int ocol = ncol0 + wc * 64 + r15;
    float bv[4];
#pragma unroll
    for (int n = 0; n < 4; ++n) bv[n] = bias[ocol + n * 16];
#pragma unroll
    for (int m = 0; m < 8; ++m) {
#pragma unroll
        for (int rr = 0; rr < 4; ++rr) {
            long orow = arow0 + wr * 128 + m * 16 + cg * 4 + rr;
            float d = dq[orow] * wmean;
#pragma unroll
            for (int n = 0; n < 4; ++n)
                out[orow * N_DIM + ocol + n * 16] = (float)acc[m][n][rr] * d + bv[n];
        }
    }
}

extern "C" void kernel_launch(void* const* d_in, const int* in_sizes, int n_in,
                              void* d_out, int out_size, void* d_ws, size_t ws_size,
                              hipStream_t stream) {
    (void)in_sizes; (void)n_in; (void)out_size; (void)ws_size;
    const float* x    = (const float*)d_in[0];
    const float* w    = (const float*)d_in[1];
    const float* bias = (const float*)d_in[2];
    float* out = (float*)d_out;

    char*   ws    = (char*)d_ws;
    char*   qx    = ws;
    char*   qw    = ws + 16777216;
    float*  dq    = (float*)(ws + 17825792);
    double* part  = (double*)(ws + 17891328);
    float*  meanf = (float*)(ws + 17893376);

    k_xq_wabs<<<dim3(4096 + 256), dim3(256), 0, stream>>>(x, w, qx, dq, part);
    k_wquant <<<dim3(1024),       dim3(256), 0, stream>>>(w, qw, part, meanf);
    k_gemm   <<<dim3(256),        dim3(512), 0, stream>>>(qx, qw, dq, meanf, bias, out);
}